// Round 2
// baseline (1464.029 us; speedup 1.0000x reference)
//
#include <hip/hip_runtime.h>
#include <hip/hip_bf16.h>

// Problem constants (fixed by setup_inputs)
#define NN 8192
#define FF 512
#define HH 256
#define RR 16
#define BB 32
#define LL 256
#define CC 7
#define EE 262144
#define NBASE 30
#define DD 768

constexpr int FLAG_BIAS = 1, FLAG_ACC = 2, FLAG_RELU = 4;

// ------------- dtype detection: are float tensors fp32 or bf16-packed? -------
// Read x (values ~N(0,1)) as ushort. If the underlying data is fp32, even
// ushorts are low mantissa halves -> as bf16, exponent bits are ~uniform ->
// ~25% have exp >= 0xC0 (|v| >= 2^64). True bf16 data never does.
__global__ __launch_bounds__(256) void detect_dtype(const unsigned short* __restrict__ xs,
                                                    int* __restrict__ flag) {
  __shared__ int red[256];
  int cnt = 0;
  for (int i = threadIdx.x * 2; i < 8192; i += 512) {
    unsigned short u = xs[i];
    int e = (u >> 7) & 0xFF;
    if (e >= 0xC0) cnt++;
  }
  red[threadIdx.x] = cnt;
  __syncthreads();
  for (int s = 128; s > 0; s >>= 1) {
    if (threadIdx.x < s) red[threadIdx.x] += red[threadIdx.x + s];
    __syncthreads();
  }
  if (threadIdx.x == 0) flag[0] = (red[0] > 16) ? 1 : 0;  // 1 = fp32 data
}

// ------------- convert any float tensor to fp32 in workspace ------------------
__global__ __launch_bounds__(256) void conv_f32(const void* __restrict__ src,
                                                float* __restrict__ dst, int n,
                                                const int* __restrict__ flag) {
  const int fp32 = flag[0];
  for (int i = blockIdx.x * 256 + threadIdx.x; i < n; i += gridDim.x * 256) {
    dst[i] = fp32 ? ((const float*)src)[i]
                  : __bfloat162float(((const __hip_bfloat16*)src)[i]);
  }
}

// ---------------- generic 64x64 tiled GEMM: C = A[M,K] @ B[K,N] ----------------
__global__ __launch_bounds__(256) void gemm_nn(
    const float* __restrict__ A, const float* __restrict__ B,
    const float* __restrict__ bias, float* __restrict__ C,
    int M, int N, int K, int lda, int ldb, int ldc,
    long sA, long sB, long sC, int flags) {
  const int bz = blockIdx.z;
  A += (long)bz * sA; B += (long)bz * sB; C += (long)bz * sC;
  __shared__ float As[16][68];
  __shared__ float Bs[16][68];
  const int tid = threadIdx.x;
  const int tx = tid & 15, ty = tid >> 4;
  const int row0 = blockIdx.y * 64, col0 = blockIdx.x * 64;
  const int am = tid >> 2, ak = (tid & 3) * 4;   // A tile: row am, k ak..ak+3
  const int bk = tid >> 4, bn = (tid & 15) * 4;  // B tile: k bk, col bn..bn+3
  float acc[4][4] = {};
  for (int k0 = 0; k0 < K; k0 += 16) {
    const float* Ap = A + (long)(row0 + am) * lda + k0 + ak;
#pragma unroll
    for (int j = 0; j < 4; ++j) As[ak + j][am] = Ap[j];
    const float* Bp = B + (long)(k0 + bk) * ldb + col0 + bn;
#pragma unroll
    for (int j = 0; j < 4; ++j) Bs[bk][bn + j] = Bp[j];
    __syncthreads();
#pragma unroll
    for (int kk = 0; kk < 16; ++kk) {
      float4 av = *(const float4*)&As[kk][ty * 4];
      float4 bv = *(const float4*)&Bs[kk][tx * 4];
      float a[4] = {av.x, av.y, av.z, av.w};
      float b[4] = {bv.x, bv.y, bv.z, bv.w};
#pragma unroll
      for (int i = 0; i < 4; ++i)
#pragma unroll
        for (int j = 0; j < 4; ++j) acc[i][j] += a[i] * b[j];
    }
    __syncthreads();
  }
#pragma unroll
  for (int i = 0; i < 4; ++i) {
    int r = row0 + ty * 4 + i;
#pragma unroll
    for (int j = 0; j < 4; ++j) {
      int c = col0 + tx * 4 + j;
      float v = acc[i][j];
      if (flags & FLAG_BIAS) v += bias[c];
      float* p = C + (long)r * ldc + c;
      if (flags & FLAG_ACC) v += *p;
      if (flags & FLAG_RELU) v = fmaxf(v, 0.f);
      *p = v;
    }
  }
}

// ---------------- batched C[m][n] = tanh(sum_k A[m][k]*B[n][k]) ----------------
__global__ __launch_bounds__(256) void gemm_nt_tanh(
    const float* __restrict__ A, const float* __restrict__ B, float* __restrict__ C,
    int K, int lda, int ldb, int ldc, long sA, long sB, long sC) {
  const int bz = blockIdx.z;
  A += (long)bz * sA; B += (long)bz * sB; C += (long)bz * sC;
  __shared__ float As[16][68];
  __shared__ float Bs[16][68];
  const int tid = threadIdx.x;
  const int tx = tid & 15, ty = tid >> 4;
  const int row0 = blockIdx.y * 64, col0 = blockIdx.x * 64;
  const int am = tid >> 2, ak = (tid & 3) * 4;
  float acc[4][4] = {};
  for (int k0 = 0; k0 < K; k0 += 16) {
    const float* Ap = A + (long)(row0 + am) * lda + k0 + ak;
#pragma unroll
    for (int j = 0; j < 4; ++j) As[ak + j][am] = Ap[j];
    const float* Bp = B + (long)(col0 + am) * ldb + k0 + ak;
#pragma unroll
    for (int j = 0; j < 4; ++j) Bs[ak + j][am] = Bp[j];
    __syncthreads();
#pragma unroll
    for (int kk = 0; kk < 16; ++kk) {
      float4 av = *(const float4*)&As[kk][ty * 4];
      float4 bv = *(const float4*)&Bs[kk][tx * 4];
      float a[4] = {av.x, av.y, av.z, av.w};
      float b[4] = {bv.x, bv.y, bv.z, bv.w};
#pragma unroll
      for (int i = 0; i < 4; ++i)
#pragma unroll
        for (int j = 0; j < 4; ++j) acc[i][j] += a[i] * b[j];
    }
    __syncthreads();
  }
#pragma unroll
  for (int i = 0; i < 4; ++i) {
    int r = row0 + ty * 4 + i;
#pragma unroll
    for (int j = 0; j < 4; ++j) {
      int c = col0 + tx * 4 + j;
      C[(long)r * ldc + c] = tanhf(acc[i][j]);
    }
  }
}

// ---------------- W_t[f][r*H+h] = sum_b comp[r,b]*basis[b,f,h] ----------------
__global__ __launch_bounds__(256) void build_wt(
    const float* __restrict__ basis, const float* __restrict__ comp,
    float* __restrict__ Wt) {
  int idx = blockIdx.x * 256 + threadIdx.x;  // 512*4096
  int f = idx >> 12;
  int rh = idx & 4095;
  int r = rh >> 8, h = rh & 255;
  float s = 0.f;
#pragma unroll 5
  for (int b = 0; b < NBASE; ++b)
    s += comp[r * NBASE + b] * basis[(((b << 9) + f) << 8) + h];
  Wt[idx] = s;
}

// ---------------- edge kernels ----------------
__global__ __launch_bounds__(256) void count_edges(
    const int* __restrict__ ei, const int* __restrict__ et, float* __restrict__ cnt) {
  int e = blockIdx.x * 256 + threadIdx.x;
  if (e < EE) atomicAdd(&cnt[ei[EE + e] * RR + et[e]], 1.0f);
}

__global__ __launch_bounds__(256) void rgcn_msg(
    const int* __restrict__ ei, const int* __restrict__ et, const float* __restrict__ cnt,
    const float* __restrict__ xw, float* __restrict__ out1) {
  int e = blockIdx.x;
  int h = threadIdx.x;
  int src = ei[e], dst = ei[EE + e], r = et[e];
  float c = cnt[dst * RR + r];
  float inv = 1.0f / fmaxf(c, 1.0f);
  float v = xw[((long)src << 12) + (r << 8) + h] * inv;
  atomicAdd(&out1[((long)dst << 8) + h], v);
}

__global__ __launch_bounds__(256) void graphconv_agg(
    const int* __restrict__ ei, const float* __restrict__ out1, float* __restrict__ agg2) {
  int e = blockIdx.x;
  int h = threadIdx.x;
  int src = ei[e], dst = ei[EE + e];
  atomicAdd(&agg2[((long)dst << 8) + h], out1[((long)src << 8) + h]);
}

// ---------------- copy x (fp32) into emotions[:, 0:512] ----------------
__global__ __launch_bounds__(256) void copy_x(
    const float* __restrict__ x, float* __restrict__ em) {
  int idx = blockIdx.x * 256 + threadIdx.x;  // 8192*512
  int n = idx >> 9, f = idx & 511;
  em[(long)n * DD + f] = x[idx];
}

// ---------------- softmax over last dim (256) ----------------
__global__ __launch_bounds__(256) void softmax256(float* __restrict__ S) {
  __shared__ float red[256];
  long row = blockIdx.x;
  float* p = S + row * 256;
  int t = threadIdx.x;
  float v = p[t];
  red[t] = v;
  __syncthreads();
  for (int s = 128; s > 0; s >>= 1) {
    if (t < s) red[t] = fmaxf(red[t], red[t + s]);
    __syncthreads();
  }
  float m = red[0];
  __syncthreads();
  float e = __expf(v - m);
  red[t] = e;
  __syncthreads();
  for (int s = 128; s > 0; s >>= 1) {
    if (t < s) red[t] += red[t + s];
    __syncthreads();
  }
  p[t] = e / red[0];
}

// ---------------- logits + log_softmax over batch axis (faithful dim=1) -------
__global__ __launch_bounds__(256) void logits_lsm(
    const float* __restrict__ hidden, const float* __restrict__ w_fc,
    const float* __restrict__ b_fc, void* __restrict__ out_v,
    const int* __restrict__ flag) {
  __shared__ float wf[256 * 7];
  __shared__ float lg[224];
  __shared__ float corr[7];
  int t = blockIdx.x;  // timestep 0..255
  int tid = threadIdx.x;
  for (int i = tid; i < 256 * 7; i += 256) wf[i] = w_fc[i];
  __syncthreads();
  if (tid < 224) {
    int b = tid / 7, c = tid % 7;
    const float* hr = hidden + ((long)((b << 8) + t) << 8);  // row b*L+t, H=256
    float s = b_fc[c];
    for (int k = 0; k < 256; ++k) s += hr[k] * wf[k * 7 + c];
    lg[tid] = s;
  }
  __syncthreads();
  if (tid < 7) {
    float m = -1e30f;
    for (int b = 0; b < BB; ++b) m = fmaxf(m, lg[b * 7 + tid]);
    float sum = 0.f;
    for (int b = 0; b < BB; ++b) sum += __expf(lg[b * 7 + tid] - m);
    corr[tid] = m + logf(sum);
  }
  __syncthreads();
  if (tid < 224) {
    float v = lg[tid] - corr[tid % 7];
    if (flag[0]) ((float*)out_v)[t * 224 + tid] = v;
    else ((__hip_bfloat16*)out_v)[t * 224 + tid] = __float2bfloat16(v);
  }
}

extern "C" void kernel_launch(void* const* d_in, const int* in_sizes, int n_in,
                              void* d_out, int out_size, void* d_ws, size_t ws_size,
                              hipStream_t stream) {
  const int* ei = (const int*)d_in[1];
  const int* et = (const int*)d_in[3];

  float* ws = (float*)d_ws;
  int* flag = (int*)d_ws;            // 16 floats reserved
  float* x_f     = ws + 16;          // 4,194,304
  float* basis_f = x_f + 4194304;    // 3,932,160
  float* comp_f  = basis_f + 3932160;// 480
  float* root1_f = comp_f + 480;     // 131,072
  float* bias1_f = root1_f + 131072; // 256
  float* w_rel_f = bias1_f + 256;    // 65,536
  float* b_rel_f = w_rel_f + 65536;  // 256
  float* w_root_f= b_rel_f + 256;    // 65,536
  float* w_att_f = w_root_f + 65536; // 589,824
  float* b_att_f = w_att_f + 589824; // 768
  float* w_lin_f = b_att_f + 768;    // 196,608
  float* b_lin_f = w_lin_f + 196608; // 256
  float* w_fc_f  = b_lin_f + 256;    // 1,792
  float* b_fc_f  = w_fc_f + 1792;    // 8 (padded)
  float* Wt   = ws + 9178880;        // 2,097,152
  float* xw   = Wt + 2097152;        // 33,554,432
  float* cnt  = xw + 33554432;       // 131,072
  float* out1 = cnt + 131072;        // 2,097,152
  float* agg2 = out1 + 2097152;      // 2,097,152  (total ~196.6 MB)
  // phase B overlays the (consumed) xw region
  float* em     = xw;                // 8192*768 = 6,291,456
  float* X      = em + 6291456;      // 6,291,456
  float* scores = X + 6291456;       // 32*256*256 = 2,097,152
  float* att    = scores + 2097152;  // 6,291,456
  float* hidden = att + 6291456;     // 2,097,152

  // 0. dtype detect + convert all float inputs to fp32
  detect_dtype<<<1, 256, 0, stream>>>((const unsigned short*)d_in[0], flag);
  auto cv = [&](int i, float* dst, int n) {
    int grid = (n + 255) / 256; if (grid > 2048) grid = 2048;
    conv_f32<<<grid, 256, 0, stream>>>(d_in[i], dst, n, flag);
  };
  cv(0, x_f, NN * FF);
  cv(8, basis_f, NBASE * FF * HH);
  cv(9, comp_f, RR * NBASE);
  cv(10, root1_f, FF * HH);
  cv(11, bias1_f, HH);
  cv(12, w_rel_f, HH * HH);
  cv(13, b_rel_f, HH);
  cv(14, w_root_f, HH * HH);
  cv(15, w_att_f, DD * DD);
  cv(16, b_att_f, DD);
  cv(17, w_lin_f, DD * HH);
  cv(18, b_lin_f, HH);
  cv(19, w_fc_f, HH * CC);
  cv(20, b_fc_f, CC);

  // 1. relation weights W_t[f][r*H+h]
  build_wt<<<(512 * 4096) / 256, 256, 0, stream>>>(basis_f, comp_f, Wt);
  // 2. xw = x @ W_t  [8192, 4096]
  gemm_nn<<<dim3(4096 / 64, NN / 64, 1), 256, 0, stream>>>(
      x_f, Wt, nullptr, xw, NN, 4096, FF, FF, 4096, 4096, 0, 0, 0, 0);
  // 3. out1 = x @ root1 + bias1
  gemm_nn<<<dim3(HH / 64, NN / 64, 1), 256, 0, stream>>>(
      x_f, root1_f, bias1_f, out1, NN, HH, FF, FF, HH, HH, 0, 0, 0, FLAG_BIAS);
  // 4. per-(dst,rel) counts; agg2 zero-init
  hipMemsetAsync(cnt, 0, 131072 * sizeof(float), stream);
  hipMemsetAsync(agg2, 0, 2097152 * sizeof(float), stream);
  count_edges<<<EE / 256, 256, 0, stream>>>(ei, et, cnt);
  // 5. out1 += mean-aggregated messages
  rgcn_msg<<<EE, 256, 0, stream>>>(ei, et, cnt, xw, out1);
  // 6. agg2 = sum_{src->dst} out1[src]
  graphconv_agg<<<EE, 256, 0, stream>>>(ei, out1, agg2);
  // 7. emotions = [x, out2]; out2 = agg2@w_rel + b_rel + out1@w_root
  copy_x<<<(NN * FF) / 256, 256, 0, stream>>>(x_f, em);
  gemm_nn<<<dim3(HH / 64, NN / 64, 1), 256, 0, stream>>>(
      agg2, w_rel_f, b_rel_f, em + FF, NN, HH, HH, HH, HH, DD, 0, 0, 0, FLAG_BIAS);
  gemm_nn<<<dim3(HH / 64, NN / 64, 1), 256, 0, stream>>>(
      out1, w_root_f, nullptr, em + FF, NN, HH, HH, HH, HH, DD, 0, 0, 0, FLAG_ACC);
  // 8. X = emotions @ w_att + b_att
  gemm_nn<<<dim3(DD / 64, NN / 64, 1), 256, 0, stream>>>(
      em, w_att_f, b_att_f, X, NN, DD, DD, DD, DD, DD, 0, 0, 0, FLAG_BIAS);
  // 9. scores[b][t][s] = tanh(X_b[t] . Em_b[s])  (mask == 1)
  gemm_nt_tanh<<<dim3(LL / 64, LL / 64, BB), 256, 0, stream>>>(
      X, em, scores, DD, DD, DD, LL, (long)LL * DD, (long)LL * DD, (long)LL * LL);
  // 10. softmax over s
  softmax256<<<BB * LL, 256, 0, stream>>>(scores);
  // 11. att_b = a_b @ Em_b
  gemm_nn<<<dim3(DD / 64, LL / 64, BB), 256, 0, stream>>>(
      scores, em, nullptr, att, LL, DD, LL, LL, DD, DD, (long)LL * LL, (long)LL * DD,
      (long)LL * DD, 0);
  // 12. hidden = relu(att @ w_lin + b_lin)
  gemm_nn<<<dim3(HH / 64, NN / 64, 1), 256, 0, stream>>>(
      att, w_lin_f, b_lin_f, hidden, NN, HH, DD, DD, HH, HH, 0, 0, 0, FLAG_BIAS | FLAG_RELU);
  // 13. logits + log_softmax over batch axis (faithful torch dim=1)
  logits_lsm<<<LL, 256, 0, stream>>>(hidden, w_fc_f, b_fc_f, d_out, flag);
}

// Round 5
// 1370.527 us; speedup vs baseline: 1.0682x; 1.0682x over previous
//
#include <hip/hip_runtime.h>
#include <hip/hip_bf16.h>

// Problem constants (fixed by setup_inputs)
#define NN 8192
#define FF 512
#define HH 256
#define RR 16
#define BB 32
#define LL 256
#define CC 7
#define EE 262144
#define NBASE 30
#define DD 768

constexpr int FLAG_BIAS = 1, FLAG_ACC = 2, FLAG_RELU = 4;

typedef __attribute__((ext_vector_type(8))) short bf16x8;
typedef __attribute__((ext_vector_type(4))) float f32x4;

// ------------- dtype detection (robustness) -----------------------------------
__global__ __launch_bounds__(256) void detect_dtype(const unsigned short* __restrict__ xs,
                                                    int* __restrict__ flag) {
  __shared__ int red[256];
  int cnt = 0;
  for (int i = threadIdx.x * 2; i < 8192; i += 512) {
    unsigned short u = xs[i];
    int e = (u >> 7) & 0xFF;
    if (e >= 0xC0) cnt++;
  }
  red[threadIdx.x] = cnt;
  __syncthreads();
  for (int s = 128; s > 0; s >>= 1) {
    if (threadIdx.x < s) red[threadIdx.x] += red[threadIdx.x + s];
    __syncthreads();
  }
  if (threadIdx.x == 0) flag[0] = (red[0] > 16) ? 1 : 0;  // 1 = fp32 data
}

__global__ __launch_bounds__(256) void conv_f32(const void* __restrict__ src,
                                                float* __restrict__ dst, int n,
                                                const int* __restrict__ flag) {
  const int fp32 = flag[0];
  for (int i = blockIdx.x * 256 + threadIdx.x; i < n; i += gridDim.x * 256)
    dst[i] = fp32 ? ((const float*)src)[i]
                  : __bfloat162float(((const __hip_bfloat16*)src)[i]);
}

// transpose + hi/lo split: src [R][C] -> hi/lo [C][R]
__global__ __launch_bounds__(256) void split_t_b16(const void* __restrict__ src,
                                                   __hip_bfloat16* __restrict__ hi,
                                                   __hip_bfloat16* __restrict__ lo,
                                                   int R, int C, const int* __restrict__ flag) {
  const int fp32 = flag[0];
  int total = R * C;
  for (int idx = blockIdx.x * 256 + threadIdx.x; idx < total; idx += gridDim.x * 256) {
    int r = idx % R, c = idx / R;
    float v = fp32 ? ((const float*)src)[(long)r * C + c]
                   : __bfloat162float(((const __hip_bfloat16*)src)[(long)r * C + c]);
    __hip_bfloat16 h = __float2bfloat16(v);
    hi[idx] = h;
    lo[idx] = __float2bfloat16(v - __bfloat162float(h));
  }
}

// hi/lo split, no transpose
__global__ __launch_bounds__(256) void split_f32(const float* __restrict__ src,
                                                 __hip_bfloat16* __restrict__ hi,
                                                 __hip_bfloat16* __restrict__ lo, int n) {
  for (int i = blockIdx.x * 256 + threadIdx.x; i < n; i += gridDim.x * 256) {
    float v = src[i];
    __hip_bfloat16 h = __float2bfloat16(v);
    hi[i] = h;
    lo[i] = __float2bfloat16(v - __bfloat162float(h));
  }
}

// ---- Wt_t[(r*H+h)][f] = sum_b comp[r,b]*basis[b,f,h], split hi/lo ------------
__global__ __launch_bounds__(256) void build_wt_t(
    const float* __restrict__ basis, const float* __restrict__ comp,
    __hip_bfloat16* __restrict__ hi, __hip_bfloat16* __restrict__ lo) {
  int idx = blockIdx.x * 256 + threadIdx.x;  // 4096*512
  int f = idx & 511, rh = idx >> 9;
  int r = rh >> 8, h = rh & 255;
  float s = 0.f;
#pragma unroll 5
  for (int b = 0; b < NBASE; ++b)
    s += comp[r * NBASE + b] * basis[(((b << 9) + f) << 8) + h];
  __hip_bfloat16 hv = __float2bfloat16(s);
  hi[idx] = hv;
  lo[idx] = __float2bfloat16(s - __bfloat162float(hv));
}

// ---------------- split-precision MFMA GEMM -----------------------------------
// C[M,N](fp32) = (Ahi+Alo)@(Bthi+Btlo)^T minus lo*lo term; 128x128 tile, BK=32,
// 4 waves (2x2 of 64x64), 16x16x32 bf16 MFMA, global_load_lds width=16.
__device__ __forceinline__ void gload_lds16(const void* g, void* l) {
  __builtin_amdgcn_global_load_lds(
      (const __attribute__((address_space(1))) unsigned int*)g,
      (__attribute__((address_space(3))) unsigned int*)l, 16, 0, 0);
}

__global__ __launch_bounds__(256) void mfma_gemm3(
    const __hip_bfloat16* __restrict__ A, const __hip_bfloat16* __restrict__ Alo,
    const __hip_bfloat16* __restrict__ Bt, const __hip_bfloat16* __restrict__ Btlo,
    const float* __restrict__ bias, float* __restrict__ C,
    int K, int ldc, int flags) {
  __shared__ __hip_bfloat16 As[128 * 32];
  __shared__ __hip_bfloat16 Bs[128 * 32];
  const int tid = threadIdx.x;
  const int w = tid >> 6, lane = tid & 63;
  const long row0 = (long)blockIdx.y * 128, col0 = (long)blockIdx.x * 128;
  const int wm = w & 1, wn = w >> 1;
  const int srow0 = (w * 128 + lane) >> 2;
  const int srow1 = (w * 128 + 64 + lane) >> 2;
  const int kch = (lane & 3) * 8;
  const int fr = lane & 15, q = lane >> 4;
  f32x4 acc[4][4] = {};
  for (int sweep = 0; sweep < 3; ++sweep) {
    const __hip_bfloat16* Ac = (sweep == 2) ? Alo : A;
    const __hip_bfloat16* Bc = (sweep == 1) ? Btlo : Bt;
    if (Ac == nullptr || Bc == nullptr) continue;
    const __hip_bfloat16* pa0 = Ac + (row0 + srow0) * K + kch;
    const __hip_bfloat16* pa1 = Ac + (row0 + srow1) * K + kch;
    const __hip_bfloat16* pb0 = Bc + (col0 + srow0) * K + kch;
    const __hip_bfloat16* pb1 = Bc + (col0 + srow1) * K + kch;
    for (int k0 = 0; k0 < K; k0 += 32) {
      gload_lds16(pa0 + k0, As + w * 1024);
      gload_lds16(pa1 + k0, As + w * 1024 + 512);
      gload_lds16(pb0 + k0, Bs + w * 1024);
      gload_lds16(pb1 + k0, Bs + w * 1024 + 512);
      __syncthreads();
      bf16x8 af[4], bfr[4];
#pragma unroll
      for (int i = 0; i < 4; ++i) {
        af[i] = *(const bf16x8*)&As[(wm * 64 + i * 16 + fr) * 32 + q * 8];
        bfr[i] = *(const bf16x8*)&Bs[(wn * 64 + i * 16 + fr) * 32 + q * 8];
      }
#pragma unroll
      for (int i = 0; i < 4; ++i)
#pragma unroll
        for (int j = 0; j < 4; ++j)
          acc[i][j] = __builtin_amdgcn_mfma_f32_16x16x32_bf16(af[i], bfr[j], acc[i][j], 0, 0, 0);
      __syncthreads();
    }
  }
  const int cr = (lane >> 4) * 4, cc = lane & 15;
#pragma unroll
  for (int i = 0; i < 4; ++i) {
    long rbase = row0 + wm * 64 + i * 16 + cr;
#pragma unroll
    for (int j = 0; j < 4; ++j) {
      long col = col0 + wn * 64 + j * 16 + cc;
      float bv = (flags & FLAG_BIAS) ? bias[col] : 0.f;
#pragma unroll
      for (int r = 0; r < 4; ++r) {
        float v = acc[i][j][r] + bv;
        if (flags & FLAG_RELU) v = fmaxf(v, 0.f);
        C[(rbase + r) * ldc + col] = v;
      }
    }
  }
}

// ---------------- fp32 64x64 tiled GEMM (accuracy-critical ops) ---------------
__global__ __launch_bounds__(256) void gemm_nn(
    const float* __restrict__ A, const float* __restrict__ B,
    const float* __restrict__ bias, float* __restrict__ C,
    int M, int N, int K, int lda, int ldb, int ldc,
    long sA, long sB, long sC, int flags) {
  const int bz = blockIdx.z;
  A += (long)bz * sA; B += (long)bz * sB; C += (long)bz * sC;
  __shared__ float As[16][68];
  __shared__ float Bs[16][68];
  const int tid = threadIdx.x;
  const int tx = tid & 15, ty = tid >> 4;
  const int row0 = blockIdx.y * 64, col0 = blockIdx.x * 64;
  const int am = tid >> 2, ak = (tid & 3) * 4;
  const int bk = tid >> 4, bn = (tid & 15) * 4;
  float acc[4][4] = {};
  for (int k0 = 0; k0 < K; k0 += 16) {
    const float* Ap = A + (long)(row0 + am) * lda + k0 + ak;
#pragma unroll
    for (int j = 0; j < 4; ++j) As[ak + j][am] = Ap[j];
    const float* Bp = B + (long)(k0 + bk) * ldb + col0 + bn;
#pragma unroll
    for (int j = 0; j < 4; ++j) Bs[bk][bn + j] = Bp[j];
    __syncthreads();
#pragma unroll
    for (int kk = 0; kk < 16; ++kk) {
      float4 av = *(const float4*)&As[kk][ty * 4];
      float4 bv = *(const float4*)&Bs[kk][tx * 4];
      float a[4] = {av.x, av.y, av.z, av.w};
      float b[4] = {bv.x, bv.y, bv.z, bv.w};
#pragma unroll
      for (int i = 0; i < 4; ++i)
#pragma unroll
        for (int j = 0; j < 4; ++j) acc[i][j] += a[i] * b[j];
    }
    __syncthreads();
  }
#pragma unroll
  for (int i = 0; i < 4; ++i) {
    int r = row0 + ty * 4 + i;
#pragma unroll
    for (int j = 0; j < 4; ++j) {
      int c = col0 + tx * 4 + j;
      float v = acc[i][j];
      if (flags & FLAG_BIAS) v += bias[c];
      float* p = C + (long)r * ldc + c;
      if (flags & FLAG_ACC) v += *p;
      if (flags & FLAG_RELU) v = fmaxf(v, 0.f);
      *p = v;
    }
  }
}

// ---------------- batched C[m][n] = tanh(sum_k A[m][k]*B[n][k]) ----------------
__global__ __launch_bounds__(256) void gemm_nt_tanh(
    const float* __restrict__ A, const float* __restrict__ B, float* __restrict__ C,
    int K, int lda, int ldb, int ldc, long sA, long sB, long sC) {
  const int bz = blockIdx.z;
  A += (long)bz * sA; B += (long)bz * sB; C += (long)bz * sC;
  __shared__ float As[16][68];
  __shared__ float Bs[16][68];
  const int tid = threadIdx.x;
  const int tx = tid & 15, ty = tid >> 4;
  const int row0 = blockIdx.y * 64, col0 = blockIdx.x * 64;
  const int am = tid >> 2, ak = (tid & 3) * 4;
  float acc[4][4] = {};
  for (int k0 = 0; k0 < K; k0 += 16) {
    const float* Ap = A + (long)(row0 + am) * lda + k0 + ak;
#pragma unroll
    for (int j = 0; j < 4; ++j) As[ak + j][am] = Ap[j];
    const float* Bp = B + (long)(col0 + am) * ldb + k0 + ak;
#pragma unroll
    for (int j = 0; j < 4; ++j) Bs[ak + j][am] = Bp[j];
    __syncthreads();
#pragma unroll
    for (int kk = 0; kk < 16; ++kk) {
      float4 av = *(const float4*)&As[kk][ty * 4];
      float4 bv = *(const float4*)&Bs[kk][tx * 4];
      float a[4] = {av.x, av.y, av.z, av.w};
      float b[4] = {bv.x, bv.y, bv.z, bv.w};
#pragma unroll
      for (int i = 0; i < 4; ++i)
#pragma unroll
        for (int j = 0; j < 4; ++j) acc[i][j] += a[i] * b[j];
    }
    __syncthreads();
  }
#pragma unroll
  for (int i = 0; i < 4; ++i) {
    int r = row0 + ty * 4 + i;
#pragma unroll
    for (int j = 0; j < 4; ++j) {
      int c = col0 + tx * 4 + j;
      C[(long)r * ldc + c] = tanhf(acc[i][j]);
    }
  }
}

// ---------------- edge kernels ----------------
__global__ __launch_bounds__(256) void count_edges(
    const int* __restrict__ ei, const int* __restrict__ et, float* __restrict__ cnt) {
  int e = blockIdx.x * 256 + threadIdx.x;
  if (e < EE) atomicAdd(&cnt[ei[EE + e] * RR + et[e]], 1.0f);
}

__global__ __launch_bounds__(256) void rgcn_msg(
    const int* __restrict__ ei, const int* __restrict__ et, const float* __restrict__ cnt,
    const float* __restrict__ xw, float* __restrict__ out1) {
  int e = blockIdx.x;
  int h = threadIdx.x;
  int src = ei[e], dst = ei[EE + e], r = et[e];
  float c = cnt[dst * RR + r];
  float inv = 1.0f / fmaxf(c, 1.0f);
  float v = xw[((long)src << 12) + (r << 8) + h] * inv;
  atomicAdd(&out1[((long)dst << 8) + h], v);
}

__global__ __launch_bounds__(256) void graphconv_agg(
    const int* __restrict__ ei, const float* __restrict__ out1, float* __restrict__ agg2) {
  int e = blockIdx.x;
  int h = threadIdx.x;
  int src = ei[e], dst = ei[EE + e];
  atomicAdd(&agg2[((long)dst << 8) + h], out1[((long)src << 8) + h]);
}

// ---------------- copy x (fp32) into emotions[:, 0:512] -----------------------
__global__ __launch_bounds__(256) void copy_x(
    const float* __restrict__ x, float* __restrict__ em) {
  int idx = blockIdx.x * 256 + threadIdx.x;  // 8192*512
  int n = idx >> 9, f = idx & 511;
  em[(long)n * DD + f] = x[idx];
}

// ---------------- softmax over last dim (256) ----------------
__global__ __launch_bounds__(256) void softmax256(float* __restrict__ S) {
  __shared__ float red[256];
  long row = blockIdx.x;
  float* p = S + row * 256;
  int t = threadIdx.x;
  float v = p[t];
  red[t] = v;
  __syncthreads();
  for (int s = 128; s > 0; s >>= 1) {
    if (t < s) red[t] = fmaxf(red[t], red[t + s]);
    __syncthreads();
  }
  float m = red[0];
  __syncthreads();
  float e = __expf(v - m);
  red[t] = e;
  __syncthreads();
  for (int s = 128; s > 0; s >>= 1) {
    if (t < s) red[t] += red[t + s];
    __syncthreads();
  }
  p[t] = e / red[0];
}

// ---------------- logits + log_softmax over batch axis (faithful dim=1) -------
__global__ __launch_bounds__(256) void logits_lsm(
    const float* __restrict__ hidden, const float* __restrict__ w_fc,
    const float* __restrict__ b_fc, void* __restrict__ out_v,
    const int* __restrict__ flag) {
  __shared__ float wf[256 * 7];
  __shared__ float lg[224];
  __shared__ float corr[7];
  int t = blockIdx.x;
  int tid = threadIdx.x;
  for (int i = tid; i < 256 * 7; i += 256) wf[i] = w_fc[i];
  __syncthreads();
  if (tid < 224) {
    int b = tid / 7, c = tid % 7;
    const float* hr = hidden + ((long)((b << 8) + t) << 8);
    float s = b_fc[c];
    for (int k = 0; k < 256; ++k) s += hr[k] * wf[k * 7 + c];
    lg[tid] = s;
  }
  __syncthreads();
  if (tid < 7) {
    float m = -1e30f;
    for (int b = 0; b < BB; ++b) m = fmaxf(m, lg[b * 7 + tid]);
    float sum = 0.f;
    for (int b = 0; b < BB; ++b) sum += __expf(lg[b * 7 + tid] - m);
    corr[tid] = m + logf(sum);
  }
  __syncthreads();
  if (tid < 224) {
    float v = lg[tid] - corr[tid % 7];
    if (flag[0]) ((float*)out_v)[t * 224 + tid] = v;
    else ((__hip_bfloat16*)out_v)[t * 224 + tid] = __float2bfloat16(v);
  }
}

extern "C" void kernel_launch(void* const* d_in, const int* in_sizes, int n_in,
                              void* d_out, int out_size, void* d_ws, size_t ws_size,
                              hipStream_t stream) {
  const int* ei = (const int*)d_in[1];
  const int* et = (const int*)d_in[3];

  float* ws = (float*)d_ws;
  int* flag = (int*)d_ws;
  float* p = ws + 16;
  auto alloc = [&](long nf) { float* r = p; p += nf; return r; };
  float* w_rel_f = alloc(65536);
  float* w_root_f = alloc(65536);
  float* w_fc_f = alloc(1792);
  float* b_rel_f = alloc(256);
  float* bias1_f = alloc(256);
  float* b_att_f = alloc(768);
  float* b_lin_f = alloc(256);
  float* b_fc_f = alloc(16);
  __hip_bfloat16* wlin_hi = (__hip_bfloat16*)alloc(98304);       // [256][768]
  __hip_bfloat16* wlin_lo = (__hip_bfloat16*)alloc(98304);
  float* x_f = alloc(4194304);                                   // [8192][512] fp32
  __hip_bfloat16* x_hi = (__hip_bfloat16*)alloc(2097152);        // [8192][512]
  __hip_bfloat16* x_lo = (__hip_bfloat16*)alloc(2097152);
  __hip_bfloat16* root1_hi = (__hip_bfloat16*)alloc(65536);      // [256][512]
  __hip_bfloat16* root1_lo = (__hip_bfloat16*)alloc(65536);
  __hip_bfloat16* watt_hi = (__hip_bfloat16*)alloc(294912);      // [768][768]
  __hip_bfloat16* watt_lo = (__hip_bfloat16*)alloc(294912);
  __hip_bfloat16* wt_hi = (__hip_bfloat16*)alloc(1048576);       // [4096][512]
  __hip_bfloat16* wt_lo = (__hip_bfloat16*)alloc(1048576);
  float* basis_f = alloc(3932160);
  float* comp_f = alloc(512);
  float* xw = alloc(33554432);   // fp32 [8192][4096]; phase-B overlay below
  float* cnt = alloc(131072);
  float* out1 = alloc(2097152);
  float* agg2 = alloc(2097152);
  float* hidden = alloc(2097152);
  // phase B overlays the (consumed) xw region — exactly fills 33,554,432 floats
  float* em = xw;                                                // 6,291,456
  __hip_bfloat16* em_hi = (__hip_bfloat16*)(em + 6291456);       // 3,145,728 f
  __hip_bfloat16* em_lo = (__hip_bfloat16*)(em + 9437184);       // 3,145,728 f
  float* X = em + 12582912;                                      // 6,291,456
  float* scores = em + 18874368;                                 // 2,097,152
  float* att = em + 20971520;                                    // 6,291,456
  __hip_bfloat16* att_hi = (__hip_bfloat16*)(em + 27262976);     // 3,145,728 f
  __hip_bfloat16* att_lo = (__hip_bfloat16*)(em + 30408704);     // 3,145,728 f

  // 0. dtype detect + conversions
  detect_dtype<<<1, 256, 0, stream>>>((const unsigned short*)d_in[0], flag);
  auto cvf = [&](int i, float* dst, int n) {
    int grid = (n + 255) / 256; if (grid > 2048) grid = 2048;
    conv_f32<<<grid, 256, 0, stream>>>(d_in[i], dst, n, flag);
  };
  cvf(0, x_f, NN * FF);
  cvf(8, basis_f, NBASE * FF * HH);
  cvf(9, comp_f, RR * NBASE);
  cvf(11, bias1_f, HH);
  cvf(12, w_rel_f, HH * HH);
  cvf(13, b_rel_f, HH);
  cvf(14, w_root_f, HH * HH);
  cvf(16, b_att_f, DD);
  cvf(18, b_lin_f, HH);
  cvf(19, w_fc_f, HH * CC);
  cvf(20, b_fc_f, CC);
  split_f32<<<2048, 256, 0, stream>>>(x_f, x_hi, x_lo, NN * FF);
  split_t_b16<<<512, 256, 0, stream>>>(d_in[10], root1_hi, root1_lo, FF, HH, flag);
  split_t_b16<<<2048, 256, 0, stream>>>(d_in[15], watt_hi, watt_lo, DD, DD, flag);
  split_t_b16<<<768, 256, 0, stream>>>(d_in[17], wlin_hi, wlin_lo, DD, HH, flag);

  // 1. Wt split hi/lo, [4096][512]
  build_wt_t<<<(4096 * 512) / 256, 256, 0, stream>>>(basis_f, comp_f, wt_hi, wt_lo);
  // 2. xw = x @ W (split A and B, 3 sweeps, fp32 out) [8192][4096]
  mfma_gemm3<<<dim3(4096 / 128, NN / 128), 256, 0, stream>>>(
      x_hi, x_lo, wt_hi, wt_lo, nullptr, xw, FF, 4096, 0);
  // 3. out1 = x @ root1 + bias1 (split A and B)
  mfma_gemm3<<<dim3(HH / 128, NN / 128), 256, 0, stream>>>(
      x_hi, x_lo, root1_hi, root1_lo, bias1_f, out1, FF, HH, FLAG_BIAS);
  // 4. per-(dst,rel) counts
  hipMemsetAsync(cnt, 0, 131072 * sizeof(float), stream);
  hipMemsetAsync(agg2, 0, 2097152 * sizeof(float), stream);
  count_edges<<<EE / 256, 256, 0, stream>>>(ei, et, cnt);
  // 5. out1 += mean-aggregated messages
  rgcn_msg<<<EE, 256, 0, stream>>>(ei, et, cnt, xw, out1);
  // 6. agg2 = sum_{src->dst} out1[src]
  graphconv_agg<<<EE, 256, 0, stream>>>(ei, out1, agg2);
  // 7. emotions = [x, out2] (fp32)
  copy_x<<<(NN * FF) / 256, 256, 0, stream>>>(x_f, em);
  gemm_nn<<<dim3(HH / 64, NN / 64, 1), 256, 0, stream>>>(
      agg2, w_rel_f, b_rel_f, em + FF, NN, HH, HH, HH, HH, DD, 0, 0, 0, FLAG_BIAS);
  gemm_nn<<<dim3(HH / 64, NN / 64, 1), 256, 0, stream>>>(
      out1, w_root_f, nullptr, em + FF, NN, HH, HH, HH, HH, DD, 0, 0, 0, FLAG_ACC);
  // 8. X = emotions @ w_att + b_att (split A and B)
  split_f32<<<2048, 256, 0, stream>>>(em, em_hi, em_lo, NN * DD);
  mfma_gemm3<<<dim3(DD / 128, NN / 128), 256, 0, stream>>>(
      em_hi, em_lo, watt_hi, watt_lo, b_att_f, X, DD, DD, FLAG_BIAS);
  // 9. scores = tanh(X_b . Em_b^T) (fp32)
  gemm_nt_tanh<<<dim3(LL / 64, LL / 64, BB), 256, 0, stream>>>(
      X, em, scores, DD, DD, DD, LL, (long)LL * DD, (long)LL * DD, (long)LL * LL);
  // 10. softmax over s
  softmax256<<<BB * LL, 256, 0, stream>>>(scores);
  // 11. att_b = a_b @ Em_b (fp32)
  gemm_nn<<<dim3(DD / 64, LL / 64, BB), 256, 0, stream>>>(
      scores, em, nullptr, att, LL, DD, LL, LL, DD, DD, (long)LL * LL, (long)LL * DD,
      (long)LL * DD, 0);
  // 12. hidden = relu(att @ w_lin + b_lin) (split A and B)
  split_f32<<<2048, 256, 0, stream>>>(att, att_hi, att_lo, NN * DD);
  mfma_gemm3<<<dim3(HH / 128, NN / 128), 256, 0, stream>>>(
      att_hi, att_lo, wlin_hi, wlin_lo, b_lin_f, hidden, DD, HH, FLAG_BIAS | FLAG_RELU);
  // 13. logits + log_softmax over batch axis
  logits_lsm<<<LL, 256, 0, stream>>>(hidden, w_fc_f, b_fc_f, d_out, flag);
}

// Round 6
// 1105.467 us; speedup vs baseline: 1.3244x; 1.2398x over previous
//
#include <hip/hip_runtime.h>
#include <hip/hip_bf16.h>

// Problem constants (fixed by setup_inputs)
#define NN 8192
#define FF 512
#define HH 256
#define RR 16
#define BB 32
#define LL 256
#define CC 7
#define EE 262144
#define NBASE 30
#define DD 768

constexpr int FLAG_BIAS = 1, FLAG_ACC = 2, FLAG_RELU = 4;

typedef __attribute__((ext_vector_type(8))) short bf16x8;
typedef __attribute__((ext_vector_type(4))) float f32x4;

// ------------- dtype detection (robustness) -----------------------------------
__global__ __launch_bounds__(256) void detect_dtype(const unsigned short* __restrict__ xs,
                                                    int* __restrict__ flag) {
  __shared__ int red[256];
  int cnt = 0;
  for (int i = threadIdx.x * 2; i < 8192; i += 512) {
    unsigned short u = xs[i];
    int e = (u >> 7) & 0xFF;
    if (e >= 0xC0) cnt++;
  }
  red[threadIdx.x] = cnt;
  __syncthreads();
  for (int s = 128; s > 0; s >>= 1) {
    if (threadIdx.x < s) red[threadIdx.x] += red[threadIdx.x + s];
    __syncthreads();
  }
  if (threadIdx.x == 0) flag[0] = (red[0] > 16) ? 1 : 0;  // 1 = fp32 data
}

__global__ __launch_bounds__(256) void conv_f32(const void* __restrict__ src,
                                                float* __restrict__ dst, int n,
                                                const int* __restrict__ flag) {
  const int fp32 = flag[0];
  for (int i = blockIdx.x * 256 + threadIdx.x; i < n; i += gridDim.x * 256)
    dst[i] = fp32 ? ((const float*)src)[i]
                  : __bfloat162float(((const __hip_bfloat16*)src)[i]);
}

// transpose + hi/lo split: src [R][C] -> hi/lo [C][R]
__global__ __launch_bounds__(256) void split_t_b16(const void* __restrict__ src,
                                                   __hip_bfloat16* __restrict__ hi,
                                                   __hip_bfloat16* __restrict__ lo,
                                                   int R, int C, const int* __restrict__ flag) {
  const int fp32 = flag[0];
  int total = R * C;
  for (int idx = blockIdx.x * 256 + threadIdx.x; idx < total; idx += gridDim.x * 256) {
    int r = idx % R, c = idx / R;
    float v = fp32 ? ((const float*)src)[(long)r * C + c]
                   : __bfloat162float(((const __hip_bfloat16*)src)[(long)r * C + c]);
    __hip_bfloat16 h = __float2bfloat16(v);
    hi[idx] = h;
    lo[idx] = __float2bfloat16(v - __bfloat162float(h));
  }
}

// hi/lo split, no transpose
__global__ __launch_bounds__(256) void split_f32(const float* __restrict__ src,
                                                 __hip_bfloat16* __restrict__ hi,
                                                 __hip_bfloat16* __restrict__ lo, int n) {
  for (int i = blockIdx.x * 256 + threadIdx.x; i < n; i += gridDim.x * 256) {
    float v = src[i];
    __hip_bfloat16 h = __float2bfloat16(v);
    hi[i] = h;
    lo[i] = __float2bfloat16(v - __bfloat162float(h));
  }
}

// ---- wt_nat[r][f][h] = sum_b comp[r,b]*basis[b][f][h] ------------------------
// basis viewed as [30][131072]; one thread per column, 16 r-accumulators.
// Reads & writes fully coalesced (basis read exactly once).
__global__ __launch_bounds__(256) void wt_gemm(
    const float* __restrict__ basis, const float* __restrict__ comp,
    float* __restrict__ wt_nat) {
  __shared__ float cs[RR * NBASE];
  int tid = threadIdx.x;
  for (int i = tid; i < RR * NBASE; i += 256) cs[i] = comp[i];
  __syncthreads();
  long col = (long)blockIdx.x * 256 + tid;  // 0..131071 (f*256+h)
  float acc[RR] = {};
  for (int b = 0; b < NBASE; ++b) {
    float v = basis[(long)b * 131072 + col];
#pragma unroll
    for (int r = 0; r < RR; ++r) acc[r] += cs[r * NBASE + b] * v;
  }
#pragma unroll
  for (int r = 0; r < RR; ++r) wt_nat[(long)r * 131072 + col] = acc[r];
}

// ---- wt_nat [16][512][256] (r,f,h) -> Wt_t[(r*256+h)][512] hi/lo -------------
// 32x32 LDS-tiled transpose per r; +1 pad kills bank conflicts.
__global__ __launch_bounds__(256) void wt_transpose(
    const float* __restrict__ wt_nat,
    __hip_bfloat16* __restrict__ hi, __hip_bfloat16* __restrict__ lo) {
  __shared__ float t[32][33];
  const int r = blockIdx.z;
  const int f0 = blockIdx.y * 32, h0 = blockIdx.x * 32;
  const int c = threadIdx.x & 31, rw = threadIdx.x >> 5;
  const float* src = wt_nat + ((long)r * 512 + f0) * 256 + h0;
#pragma unroll
  for (int i = 0; i < 4; ++i)
    t[rw + i * 8][c] = src[(long)(rw + i * 8) * 256 + c];  // t[f_loc][h_loc]
  __syncthreads();
#pragma unroll
  for (int i = 0; i < 4; ++i) {
    int hh = rw + i * 8;                 // h_loc
    float v = t[c][hh];                  // lane c -> f_loc (coalesced write)
    long orow = (long)(r * 256 + h0 + hh) * 512 + f0 + c;
    __hip_bfloat16 hv = __float2bfloat16(v);
    hi[orow] = hv;
    lo[orow] = __float2bfloat16(v - __bfloat162float(hv));
  }
}

// ---------------- split-precision MFMA GEMM -----------------------------------
// C[M,N](fp32) = (Ahi+Alo)@(Bthi+Btlo)^T minus lo*lo term; 128x128 tile, BK=32,
// 4 waves (2x2 of 64x64), 16x16x32 bf16 MFMA, global_load_lds width=16.
__device__ __forceinline__ void gload_lds16(const void* g, void* l) {
  __builtin_amdgcn_global_load_lds(
      (const __attribute__((address_space(1))) unsigned int*)g,
      (__attribute__((address_space(3))) unsigned int*)l, 16, 0, 0);
}

__global__ __launch_bounds__(256) void mfma_gemm3(
    const __hip_bfloat16* __restrict__ A, const __hip_bfloat16* __restrict__ Alo,
    const __hip_bfloat16* __restrict__ Bt, const __hip_bfloat16* __restrict__ Btlo,
    const float* __restrict__ bias, float* __restrict__ C,
    int K, int ldc, int flags) {
  __shared__ __hip_bfloat16 As[128 * 32];
  __shared__ __hip_bfloat16 Bs[128 * 32];
  const int tid = threadIdx.x;
  const int w = tid >> 6, lane = tid & 63;
  const long row0 = (long)blockIdx.y * 128, col0 = (long)blockIdx.x * 128;
  const int wm = w & 1, wn = w >> 1;
  const int srow0 = (w * 128 + lane) >> 2;
  const int srow1 = (w * 128 + 64 + lane) >> 2;
  const int kch = (lane & 3) * 8;
  const int fr = lane & 15, q = lane >> 4;
  f32x4 acc[4][4] = {};
  for (int sweep = 0; sweep < 3; ++sweep) {
    const __hip_bfloat16* Ac = (sweep == 2) ? Alo : A;
    const __hip_bfloat16* Bc = (sweep == 1) ? Btlo : Bt;
    if (Ac == nullptr || Bc == nullptr) continue;
    const __hip_bfloat16* pa0 = Ac + (row0 + srow0) * K + kch;
    const __hip_bfloat16* pa1 = Ac + (row0 + srow1) * K + kch;
    const __hip_bfloat16* pb0 = Bc + (col0 + srow0) * K + kch;
    const __hip_bfloat16* pb1 = Bc + (col0 + srow1) * K + kch;
    for (int k0 = 0; k0 < K; k0 += 32) {
      gload_lds16(pa0 + k0, As + w * 1024);
      gload_lds16(pa1 + k0, As + w * 1024 + 512);
      gload_lds16(pb0 + k0, Bs + w * 1024);
      gload_lds16(pb1 + k0, Bs + w * 1024 + 512);
      __syncthreads();
      bf16x8 af[4], bfr[4];
#pragma unroll
      for (int i = 0; i < 4; ++i) {
        af[i] = *(const bf16x8*)&As[(wm * 64 + i * 16 + fr) * 32 + q * 8];
        bfr[i] = *(const bf16x8*)&Bs[(wn * 64 + i * 16 + fr) * 32 + q * 8];
      }
#pragma unroll
      for (int i = 0; i < 4; ++i)
#pragma unroll
        for (int j = 0; j < 4; ++j)
          acc[i][j] = __builtin_amdgcn_mfma_f32_16x16x32_bf16(af[i], bfr[j], acc[i][j], 0, 0, 0);
      __syncthreads();
    }
  }
  const int cr = (lane >> 4) * 4, cc = lane & 15;
#pragma unroll
  for (int i = 0; i < 4; ++i) {
    long rbase = row0 + wm * 64 + i * 16 + cr;
#pragma unroll
    for (int j = 0; j < 4; ++j) {
      long col = col0 + wn * 64 + j * 16 + cc;
      float bv = (flags & FLAG_BIAS) ? bias[col] : 0.f;
#pragma unroll
      for (int r = 0; r < 4; ++r) {
        float v = acc[i][j][r] + bv;
        if (flags & FLAG_RELU) v = fmaxf(v, 0.f);
        C[(rbase + r) * ldc + col] = v;
      }
    }
  }
}

// ---------------- fp32 64x64 tiled GEMM (accuracy-critical ops) ---------------
__global__ __launch_bounds__(256) void gemm_nn(
    const float* __restrict__ A, const float* __restrict__ B,
    const float* __restrict__ bias, float* __restrict__ C,
    int M, int N, int K, int lda, int ldb, int ldc,
    long sA, long sB, long sC, int flags) {
  const int bz = blockIdx.z;
  A += (long)bz * sA; B += (long)bz * sB; C += (long)bz * sC;
  __shared__ float As[16][68];
  __shared__ float Bs[16][68];
  const int tid = threadIdx.x;
  const int tx = tid & 15, ty = tid >> 4;
  const int row0 = blockIdx.y * 64, col0 = blockIdx.x * 64;
  const int am = tid >> 2, ak = (tid & 3) * 4;
  const int bk = tid >> 4, bn = (tid & 15) * 4;
  float acc[4][4] = {};
  for (int k0 = 0; k0 < K; k0 += 16) {
    const float* Ap = A + (long)(row0 + am) * lda + k0 + ak;
#pragma unroll
    for (int j = 0; j < 4; ++j) As[ak + j][am] = Ap[j];
    const float* Bp = B + (long)(k0 + bk) * ldb + col0 + bn;
#pragma unroll
    for (int j = 0; j < 4; ++j) Bs[bk][bn + j] = Bp[j];
    __syncthreads();
#pragma unroll
    for (int kk = 0; kk < 16; ++kk) {
      float4 av = *(const float4*)&As[kk][ty * 4];
      float4 bv = *(const float4*)&Bs[kk][tx * 4];
      float a[4] = {av.x, av.y, av.z, av.w};
      float b[4] = {bv.x, bv.y, bv.z, bv.w};
#pragma unroll
      for (int i = 0; i < 4; ++i)
#pragma unroll
        for (int j = 0; j < 4; ++j) acc[i][j] += a[i] * b[j];
    }
    __syncthreads();
  }
#pragma unroll
  for (int i = 0; i < 4; ++i) {
    int r = row0 + ty * 4 + i;
#pragma unroll
    for (int j = 0; j < 4; ++j) {
      int c = col0 + tx * 4 + j;
      float v = acc[i][j];
      if (flags & FLAG_BIAS) v += bias[c];
      float* p = C + (long)r * ldc + c;
      if (flags & FLAG_ACC) v += *p;
      if (flags & FLAG_RELU) v = fmaxf(v, 0.f);
      *p = v;
    }
  }
}

// ---------------- batched C[m][n] = tanh(sum_k A[m][k]*B[n][k]) ----------------
__global__ __launch_bounds__(256) void gemm_nt_tanh(
    const float* __restrict__ A, const float* __restrict__ B, float* __restrict__ C,
    int K, int lda, int ldb, int ldc, long sA, long sB, long sC) {
  const int bz = blockIdx.z;
  A += (long)bz * sA; B += (long)bz * sB; C += (long)bz * sC;
  __shared__ float As[16][68];
  __shared__ float Bs[16][68];
  const int tid = threadIdx.x;
  const int tx = tid & 15, ty = tid >> 4;
  const int row0 = blockIdx.y * 64, col0 = blockIdx.x * 64;
  const int am = tid >> 2, ak = (tid & 3) * 4;
  float acc[4][4] = {};
  for (int k0 = 0; k0 < K; k0 += 16) {
    const float* Ap = A + (long)(row0 + am) * lda + k0 + ak;
#pragma unroll
    for (int j = 0; j < 4; ++j) As[ak + j][am] = Ap[j];
    const float* Bp = B + (long)(col0 + am) * ldb + k0 + ak;
#pragma unroll
    for (int j = 0; j < 4; ++j) Bs[ak + j][am] = Bp[j];
    __syncthreads();
#pragma unroll
    for (int kk = 0; kk < 16; ++kk) {
      float4 av = *(const float4*)&As[kk][ty * 4];
      float4 bv = *(const float4*)&Bs[kk][tx * 4];
      float a[4] = {av.x, av.y, av.z, av.w};
      float b[4] = {bv.x, bv.y, bv.z, bv.w};
#pragma unroll
      for (int i = 0; i < 4; ++i)
#pragma unroll
        for (int j = 0; j < 4; ++j) acc[i][j] += a[i] * b[j];
    }
    __syncthreads();
  }
#pragma unroll
  for (int i = 0; i < 4; ++i) {
    int r = row0 + ty * 4 + i;
#pragma unroll
    for (int j = 0; j < 4; ++j) {
      int c = col0 + tx * 4 + j;
      C[(long)r * ldc + c] = tanhf(acc[i][j]);
    }
  }
}

// ---------------- edge kernels ----------------
__global__ __launch_bounds__(256) void count_edges(
    const int* __restrict__ ei, const int* __restrict__ et, float* __restrict__ cnt) {
  int e = blockIdx.x * 256 + threadIdx.x;
  if (e < EE) atomicAdd(&cnt[ei[EE + e] * RR + et[e]], 1.0f);
}

__global__ __launch_bounds__(256) void rgcn_msg(
    const int* __restrict__ ei, const int* __restrict__ et, const float* __restrict__ cnt,
    const float* __restrict__ xw, float* __restrict__ out1) {
  int e = blockIdx.x;
  int h = threadIdx.x;
  int src = ei[e], dst = ei[EE + e], r = et[e];
  float c = cnt[dst * RR + r];
  float inv = 1.0f / fmaxf(c, 1.0f);
  float v = xw[((long)src << 12) + (r << 8) + h] * inv;
  atomicAdd(&out1[((long)dst << 8) + h], v);
}

__global__ __launch_bounds__(256) void graphconv_agg(
    const int* __restrict__ ei, const float* __restrict__ out1, float* __restrict__ agg2) {
  int e = blockIdx.x;
  int h = threadIdx.x;
  int src = ei[e], dst = ei[EE + e];
  atomicAdd(&agg2[((long)dst << 8) + h], out1[((long)src << 8) + h]);
}

// ---------------- copy x (fp32) into emotions[:, 0:512] -----------------------
__global__ __launch_bounds__(256) void copy_x(
    const float* __restrict__ x, float* __restrict__ em) {
  int idx = blockIdx.x * 256 + threadIdx.x;  // 8192*512
  int n = idx >> 9, f = idx & 511;
  em[(long)n * DD + f] = x[idx];
}

// ---------------- softmax over last dim (256) ----------------
__global__ __launch_bounds__(256) void softmax256(float* __restrict__ S) {
  __shared__ float red[256];
  long row = blockIdx.x;
  float* p = S + row * 256;
  int t = threadIdx.x;
  float v = p[t];
  red[t] = v;
  __syncthreads();
  for (int s = 128; s > 0; s >>= 1) {
    if (t < s) red[t] = fmaxf(red[t], red[t + s]);
    __syncthreads();
  }
  float m = red[0];
  __syncthreads();
  float e = __expf(v - m);
  red[t] = e;
  __syncthreads();
  for (int s = 128; s > 0; s >>= 1) {
    if (t < s) red[t] += red[t + s];
    __syncthreads();
  }
  p[t] = e / red[0];
}

// ---------------- logits + log_softmax over batch axis (faithful dim=1) -------
__global__ __launch_bounds__(256) void logits_lsm(
    const float* __restrict__ hidden, const float* __restrict__ w_fc,
    const float* __restrict__ b_fc, void* __restrict__ out_v,
    const int* __restrict__ flag) {
  __shared__ float wf[256 * 7];
  __shared__ float lg[224];
  __shared__ float corr[7];
  int t = blockIdx.x;
  int tid = threadIdx.x;
  for (int i = tid; i < 256 * 7; i += 256) wf[i] = w_fc[i];
  __syncthreads();
  if (tid < 224) {
    int b = tid / 7, c = tid % 7;
    const float* hr = hidden + ((long)((b << 8) + t) << 8);
    float s = b_fc[c];
    for (int k = 0; k < 256; ++k) s += hr[k] * wf[k * 7 + c];
    lg[tid] = s;
  }
  __syncthreads();
  if (tid < 7) {
    float m = -1e30f;
    for (int b = 0; b < BB; ++b) m = fmaxf(m, lg[b * 7 + tid]);
    float sum = 0.f;
    for (int b = 0; b < BB; ++b) sum += __expf(lg[b * 7 + tid] - m);
    corr[tid] = m + logf(sum);
  }
  __syncthreads();
  if (tid < 224) {
    float v = lg[tid] - corr[tid % 7];
    if (flag[0]) ((float*)out_v)[t * 224 + tid] = v;
    else ((__hip_bfloat16*)out_v)[t * 224 + tid] = __float2bfloat16(v);
  }
}

extern "C" void kernel_launch(void* const* d_in, const int* in_sizes, int n_in,
                              void* d_out, int out_size, void* d_ws, size_t ws_size,
                              hipStream_t stream) {
  const int* ei = (const int*)d_in[1];
  const int* et = (const int*)d_in[3];

  float* ws = (float*)d_ws;
  int* flag = (int*)d_ws;
  float* p = ws + 16;
  auto alloc = [&](long nf) { float* r = p; p += nf; return r; };
  float* w_rel_f = alloc(65536);
  float* w_root_f = alloc(65536);
  float* w_fc_f = alloc(1792);
  float* b_rel_f = alloc(256);
  float* bias1_f = alloc(256);
  float* b_att_f = alloc(768);
  float* b_lin_f = alloc(256);
  float* b_fc_f = alloc(16);
  __hip_bfloat16* wlin_hi = (__hip_bfloat16*)alloc(98304);       // [256][768]
  __hip_bfloat16* wlin_lo = (__hip_bfloat16*)alloc(98304);
  float* x_f = alloc(4194304);                                   // [8192][512] fp32
  __hip_bfloat16* x_hi = (__hip_bfloat16*)alloc(2097152);        // [8192][512]
  __hip_bfloat16* x_lo = (__hip_bfloat16*)alloc(2097152);
  __hip_bfloat16* root1_hi = (__hip_bfloat16*)alloc(65536);      // [256][512]
  __hip_bfloat16* root1_lo = (__hip_bfloat16*)alloc(65536);
  __hip_bfloat16* watt_hi = (__hip_bfloat16*)alloc(294912);      // [768][768]
  __hip_bfloat16* watt_lo = (__hip_bfloat16*)alloc(294912);
  __hip_bfloat16* wt_hi = (__hip_bfloat16*)alloc(1048576);       // [4096][512]
  __hip_bfloat16* wt_lo = (__hip_bfloat16*)alloc(1048576);
  float* basis_f = alloc(3932160);
  float* comp_f = alloc(512);
  float* xw = alloc(33554432);   // fp32 [8192][4096]; overlays below
  float* cnt = alloc(131072);
  float* out1 = alloc(2097152);
  float* agg2 = alloc(2097152);
  float* hidden = alloc(2097152);
  // wt_nat overlays head of xw (consumed by wt_transpose before xw is written)
  float* wt_nat = xw;                                            // [16][512][256]
  // phase B overlays the (consumed) xw region — exactly fills 33,554,432 floats
  float* em = xw;                                                // 6,291,456
  __hip_bfloat16* em_hi = (__hip_bfloat16*)(em + 6291456);       // 3,145,728 f
  __hip_bfloat16* em_lo = (__hip_bfloat16*)(em + 9437184);       // 3,145,728 f
  float* X = em + 12582912;                                      // 6,291,456
  float* scores = em + 18874368;                                 // 2,097,152
  float* att = em + 20971520;                                    // 6,291,456
  __hip_bfloat16* att_hi = (__hip_bfloat16*)(em + 27262976);     // 3,145,728 f
  __hip_bfloat16* att_lo = (__hip_bfloat16*)(em + 30408704);     // 3,145,728 f

  // 0. dtype detect + conversions
  detect_dtype<<<1, 256, 0, stream>>>((const unsigned short*)d_in[0], flag);
  auto cvf = [&](int i, float* dst, int n) {
    int grid = (n + 255) / 256; if (grid > 2048) grid = 2048;
    conv_f32<<<grid, 256, 0, stream>>>(d_in[i], dst, n, flag);
  };
  cvf(0, x_f, NN * FF);
  cvf(8, basis_f, NBASE * FF * HH);
  cvf(9, comp_f, RR * NBASE);
  cvf(11, bias1_f, HH);
  cvf(12, w_rel_f, HH * HH);
  cvf(13, b_rel_f, HH);
  cvf(14, w_root_f, HH * HH);
  cvf(16, b_att_f, DD);
  cvf(18, b_lin_f, HH);
  cvf(19, w_fc_f, HH * CC);
  cvf(20, b_fc_f, CC);
  split_f32<<<2048, 256, 0, stream>>>(x_f, x_hi, x_lo, NN * FF);
  split_t_b16<<<512, 256, 0, stream>>>(d_in[10], root1_hi, root1_lo, FF, HH, flag);
  split_t_b16<<<2048, 256, 0, stream>>>(d_in[15], watt_hi, watt_lo, DD, DD, flag);
  split_t_b16<<<768, 256, 0, stream>>>(d_in[17], wlin_hi, wlin_lo, DD, HH, flag);

  // 1. Wt: coalesced GEMM into natural layout, then LDS-tiled transpose + split
  wt_gemm<<<131072 / 256, 256, 0, stream>>>(basis_f, comp_f, wt_nat);
  wt_transpose<<<dim3(8, 16, 16), 256, 0, stream>>>(wt_nat, wt_hi, wt_lo);
  // 2. xw = x @ W (split A and B, 3 sweeps, fp32 out) [8192][4096]
  mfma_gemm3<<<dim3(4096 / 128, NN / 128), 256, 0, stream>>>(
      x_hi, x_lo, wt_hi, wt_lo, nullptr, xw, FF, 4096, 0);
  // 3. out1 = x @ root1 + bias1 (split A and B)
  mfma_gemm3<<<dim3(HH / 128, NN / 128), 256, 0, stream>>>(
      x_hi, x_lo, root1_hi, root1_lo, bias1_f, out1, FF, HH, FLAG_BIAS);
  // 4. per-(dst,rel) counts
  hipMemsetAsync(cnt, 0, 131072 * sizeof(float), stream);
  hipMemsetAsync(agg2, 0, 2097152 * sizeof(float), stream);
  count_edges<<<EE / 256, 256, 0, stream>>>(ei, et, cnt);
  // 5. out1 += mean-aggregated messages
  rgcn_msg<<<EE, 256, 0, stream>>>(ei, et, cnt, xw, out1);
  // 6. agg2 = sum_{src->dst} out1[src]
  graphconv_agg<<<EE, 256, 0, stream>>>(ei, out1, agg2);
  // 7. emotions = [x, out2] (fp32)
  copy_x<<<(NN * FF) / 256, 256, 0, stream>>>(x_f, em);
  gemm_nn<<<dim3(HH / 64, NN / 64, 1), 256, 0, stream>>>(
      agg2, w_rel_f, b_rel_f, em + FF, NN, HH, HH, HH, HH, DD, 0, 0, 0, FLAG_BIAS);
  gemm_nn<<<dim3(HH / 64, NN / 64, 1), 256, 0, stream>>>(
      out1, w_root_f, nullptr, em + FF, NN, HH, HH, HH, HH, DD, 0, 0, 0, FLAG_ACC);
  // 8. X = emotions @ w_att + b_att (split A and B)
  split_f32<<<2048, 256, 0, stream>>>(em, em_hi, em_lo, NN * DD);
  mfma_gemm3<<<dim3(DD / 128, NN / 128), 256, 0, stream>>>(
      em_hi, em_lo, watt_hi, watt_lo, b_att_f, X, DD, DD, FLAG_BIAS);
  // 9. scores = tanh(X_b . Em_b^T) (fp32)
  gemm_nt_tanh<<<dim3(LL / 64, LL / 64, BB), 256, 0, stream>>>(
      X, em, scores, DD, DD, DD, LL, (long)LL * DD, (long)LL * DD, (long)LL * LL);
  // 10. softmax over s
  softmax256<<<BB * LL, 256, 0, stream>>>(scores);
  // 11. att_b = a_b @ Em_b (fp32)
  gemm_nn<<<dim3(DD / 64, LL / 64, BB), 256, 0, stream>>>(
      scores, em, nullptr, att, LL, DD, LL, LL, DD, DD, (long)LL * LL, (long)LL * DD,
      (long)LL * DD, 0);
  // 12. hidden = relu(att @ w_lin + b_lin) (split A and B)
  split_f32<<<2048, 256, 0, stream>>>(att, att_hi, att_lo, NN * DD);
  mfma_gemm3<<<dim3(HH / 128, NN / 128), 256, 0, stream>>>(
      att_hi, att_lo, wlin_hi, wlin_lo, b_lin_f, hidden, DD, HH, FLAG_BIAS | FLAG_RELU);
  // 13. logits + log_softmax over batch axis
  logits_lsm<<<LL, 256, 0, stream>>>(hidden, w_fc_f, b_fc_f, d_out, flag);
}

// Round 7
// 774.304 us; speedup vs baseline: 1.8908x; 1.4277x over previous
//
#include <hip/hip_runtime.h>
#include <hip/hip_bf16.h>

// Problem constants (fixed by setup_inputs)
#define NN 8192
#define FF 512
#define HH 256
#define RR 16
#define BB 32
#define LL 256
#define CC 7
#define EE 262144
#define NBASE 30
#define DD 768

constexpr int FLAG_BIAS = 1, FLAG_ACC = 2, FLAG_RELU = 4;

typedef __attribute__((ext_vector_type(8))) short bf16x8;
typedef __attribute__((ext_vector_type(4))) float f32x4;

// ------------- dtype detection (robustness) -----------------------------------
__global__ __launch_bounds__(256) void detect_dtype(const unsigned short* __restrict__ xs,
                                                    int* __restrict__ flag) {
  __shared__ int red[256];
  int cnt = 0;
  for (int i = threadIdx.x * 2; i < 8192; i += 512) {
    unsigned short u = xs[i];
    int e = (u >> 7) & 0xFF;
    if (e >= 0xC0) cnt++;
  }
  red[threadIdx.x] = cnt;
  __syncthreads();
  for (int s = 128; s > 0; s >>= 1) {
    if (threadIdx.x < s) red[threadIdx.x] += red[threadIdx.x + s];
    __syncthreads();
  }
  if (threadIdx.x == 0) flag[0] = (red[0] > 16) ? 1 : 0;  // 1 = fp32 data
}

__global__ __launch_bounds__(256) void conv_f32(const void* __restrict__ src,
                                                float* __restrict__ dst, int n,
                                                const int* __restrict__ flag) {
  const int fp32 = flag[0];
  for (int i = blockIdx.x * 256 + threadIdx.x; i < n; i += gridDim.x * 256)
    dst[i] = fp32 ? ((const float*)src)[i]
                  : __bfloat162float(((const __hip_bfloat16*)src)[i]);
}

// transpose + hi/lo split: src [R][C] -> hi/lo [C][R]
__global__ __launch_bounds__(256) void split_t_b16(const void* __restrict__ src,
                                                   __hip_bfloat16* __restrict__ hi,
                                                   __hip_bfloat16* __restrict__ lo,
                                                   int R, int C, const int* __restrict__ flag) {
  const int fp32 = flag[0];
  int total = R * C;
  for (int idx = blockIdx.x * 256 + threadIdx.x; idx < total; idx += gridDim.x * 256) {
    int r = idx % R, c = idx / R;
    float v = fp32 ? ((const float*)src)[(long)r * C + c]
                   : __bfloat162float(((const __hip_bfloat16*)src)[(long)r * C + c]);
    __hip_bfloat16 h = __float2bfloat16(v);
    hi[idx] = h;
    lo[idx] = __float2bfloat16(v - __bfloat162float(h));
  }
}

// hi/lo split, no transpose
__global__ __launch_bounds__(256) void split_f32(const float* __restrict__ src,
                                                 __hip_bfloat16* __restrict__ hi,
                                                 __hip_bfloat16* __restrict__ lo, int n) {
  for (int i = blockIdx.x * 256 + threadIdx.x; i < n; i += gridDim.x * 256) {
    float v = src[i];
    __hip_bfloat16 h = __float2bfloat16(v);
    hi[i] = h;
    lo[i] = __float2bfloat16(v - __bfloat162float(h));
  }
}

// ---- wt_nat[r][f][h] = sum_b comp[r,b]*basis[b][f][h] ------------------------
__global__ __launch_bounds__(256) void wt_gemm(
    const float* __restrict__ basis, const float* __restrict__ comp,
    float* __restrict__ wt_nat) {
  __shared__ float cs[RR * NBASE];
  int tid = threadIdx.x;
  for (int i = tid; i < RR * NBASE; i += 256) cs[i] = comp[i];
  __syncthreads();
  long col = (long)blockIdx.x * 256 + tid;  // 0..131071 (f*256+h)
  float acc[RR] = {};
  for (int b = 0; b < NBASE; ++b) {
    float v = basis[(long)b * 131072 + col];
#pragma unroll
    for (int r = 0; r < RR; ++r) acc[r] += cs[r * NBASE + b] * v;
  }
#pragma unroll
  for (int r = 0; r < RR; ++r) wt_nat[(long)r * 131072 + col] = acc[r];
}

// ---- wt_nat [16][512][256] (r,f,h) -> Wt_t[(r*256+h)][512] hi/lo -------------
__global__ __launch_bounds__(256) void wt_transpose(
    const float* __restrict__ wt_nat,
    __hip_bfloat16* __restrict__ hi, __hip_bfloat16* __restrict__ lo) {
  __shared__ float t[32][33];
  const int r = blockIdx.z;
  const int f0 = blockIdx.y * 32, h0 = blockIdx.x * 32;
  const int c = threadIdx.x & 31, rw = threadIdx.x >> 5;
  const float* src = wt_nat + ((long)r * 512 + f0) * 256 + h0;
#pragma unroll
  for (int i = 0; i < 4; ++i)
    t[rw + i * 8][c] = src[(long)(rw + i * 8) * 256 + c];  // t[f_loc][h_loc]
  __syncthreads();
#pragma unroll
  for (int i = 0; i < 4; ++i) {
    int hh = rw + i * 8;                 // h_loc
    float v = t[c][hh];                  // lane c -> f_loc (coalesced write)
    long orow = (long)(r * 256 + h0 + hh) * 512 + f0 + c;
    __hip_bfloat16 hv = __float2bfloat16(v);
    hi[orow] = hv;
    lo[orow] = __float2bfloat16(v - __bfloat162float(hv));
  }
}

// ---------------- split-precision MFMA GEMM -----------------------------------
__device__ __forceinline__ void gload_lds16(const void* g, void* l) {
  __builtin_amdgcn_global_load_lds(
      (const __attribute__((address_space(1))) unsigned int*)g,
      (__attribute__((address_space(3))) unsigned int*)l, 16, 0, 0);
}

__global__ __launch_bounds__(256) void mfma_gemm3(
    const __hip_bfloat16* __restrict__ A, const __hip_bfloat16* __restrict__ Alo,
    const __hip_bfloat16* __restrict__ Bt, const __hip_bfloat16* __restrict__ Btlo,
    const float* __restrict__ bias, float* __restrict__ C,
    int K, int ldc, int flags) {
  __shared__ __hip_bfloat16 As[128 * 32];
  __shared__ __hip_bfloat16 Bs[128 * 32];
  const int tid = threadIdx.x;
  const int w = tid >> 6, lane = tid & 63;
  const long row0 = (long)blockIdx.y * 128, col0 = (long)blockIdx.x * 128;
  const int wm = w & 1, wn = w >> 1;
  const int srow0 = (w * 128 + lane) >> 2;
  const int srow1 = (w * 128 + 64 + lane) >> 2;
  const int kch = (lane & 3) * 8;
  const int fr = lane & 15, q = lane >> 4;
  f32x4 acc[4][4] = {};
  for (int sweep = 0; sweep < 3; ++sweep) {
    const __hip_bfloat16* Ac = (sweep == 2) ? Alo : A;
    const __hip_bfloat16* Bc = (sweep == 1) ? Btlo : Bt;
    if (Ac == nullptr || Bc == nullptr) continue;
    const __hip_bfloat16* pa0 = Ac + (row0 + srow0) * K + kch;
    const __hip_bfloat16* pa1 = Ac + (row0 + srow1) * K + kch;
    const __hip_bfloat16* pb0 = Bc + (col0 + srow0) * K + kch;
    const __hip_bfloat16* pb1 = Bc + (col0 + srow1) * K + kch;
    for (int k0 = 0; k0 < K; k0 += 32) {
      gload_lds16(pa0 + k0, As + w * 1024);
      gload_lds16(pa1 + k0, As + w * 1024 + 512);
      gload_lds16(pb0 + k0, Bs + w * 1024);
      gload_lds16(pb1 + k0, Bs + w * 1024 + 512);
      __syncthreads();
      bf16x8 af[4], bfr[4];
#pragma unroll
      for (int i = 0; i < 4; ++i) {
        af[i] = *(const bf16x8*)&As[(wm * 64 + i * 16 + fr) * 32 + q * 8];
        bfr[i] = *(const bf16x8*)&Bs[(wn * 64 + i * 16 + fr) * 32 + q * 8];
      }
#pragma unroll
      for (int i = 0; i < 4; ++i)
#pragma unroll
        for (int j = 0; j < 4; ++j)
          acc[i][j] = __builtin_amdgcn_mfma_f32_16x16x32_bf16(af[i], bfr[j], acc[i][j], 0, 0, 0);
      __syncthreads();
    }
  }
  const int cr = (lane >> 4) * 4, cc = lane & 15;
#pragma unroll
  for (int i = 0; i < 4; ++i) {
    long rbase = row0 + wm * 64 + i * 16 + cr;
#pragma unroll
    for (int j = 0; j < 4; ++j) {
      long col = col0 + wn * 64 + j * 16 + cc;
      float bv = (flags & FLAG_BIAS) ? bias[col] : 0.f;
#pragma unroll
      for (int r = 0; r < 4; ++r) {
        float v = acc[i][j][r] + bv;
        if (flags & FLAG_RELU) v = fmaxf(v, 0.f);
        C[(rbase + r) * ldc + col] = v;
      }
    }
  }
}

// ---------------- fp32 64x64 tiled GEMM (accuracy-critical ops) ---------------
__global__ __launch_bounds__(256) void gemm_nn(
    const float* __restrict__ A, const float* __restrict__ B,
    const float* __restrict__ bias, float* __restrict__ C,
    int M, int N, int K, int lda, int ldb, int ldc,
    long sA, long sB, long sC, int flags) {
  const int bz = blockIdx.z;
  A += (long)bz * sA; B += (long)bz * sB; C += (long)bz * sC;
  __shared__ float As[16][68];
  __shared__ float Bs[16][68];
  const int tid = threadIdx.x;
  const int tx = tid & 15, ty = tid >> 4;
  const int row0 = blockIdx.y * 64, col0 = blockIdx.x * 64;
  const int am = tid >> 2, ak = (tid & 3) * 4;
  const int bk = tid >> 4, bn = (tid & 15) * 4;
  float acc[4][4] = {};
  for (int k0 = 0; k0 < K; k0 += 16) {
    const float* Ap = A + (long)(row0 + am) * lda + k0 + ak;
#pragma unroll
    for (int j = 0; j < 4; ++j) As[ak + j][am] = Ap[j];
    const float* Bp = B + (long)(k0 + bk) * ldb + col0 + bn;
#pragma unroll
    for (int j = 0; j < 4; ++j) Bs[bk][bn + j] = Bp[j];
    __syncthreads();
#pragma unroll
    for (int kk = 0; kk < 16; ++kk) {
      float4 av = *(const float4*)&As[kk][ty * 4];
      float4 bv = *(const float4*)&Bs[kk][tx * 4];
      float a[4] = {av.x, av.y, av.z, av.w};
      float b[4] = {bv.x, bv.y, bv.z, bv.w};
#pragma unroll
      for (int i = 0; i < 4; ++i)
#pragma unroll
        for (int j = 0; j < 4; ++j) acc[i][j] += a[i] * b[j];
    }
    __syncthreads();
  }
#pragma unroll
  for (int i = 0; i < 4; ++i) {
    int r = row0 + ty * 4 + i;
#pragma unroll
    for (int j = 0; j < 4; ++j) {
      int c = col0 + tx * 4 + j;
      float v = acc[i][j];
      if (flags & FLAG_BIAS) v += bias[c];
      float* p = C + (long)r * ldc + c;
      if (flags & FLAG_ACC) v += *p;
      if (flags & FLAG_RELU) v = fmaxf(v, 0.f);
      *p = v;
    }
  }
}

// ---------------- batched C[m][n] = tanh(sum_k A[m][k]*B[n][k]) ----------------
__global__ __launch_bounds__(256) void gemm_nt_tanh(
    const float* __restrict__ A, const float* __restrict__ B, float* __restrict__ C,
    int K, int lda, int ldb, int ldc, long sA, long sB, long sC) {
  const int bz = blockIdx.z;
  A += (long)bz * sA; B += (long)bz * sB; C += (long)bz * sC;
  __shared__ float As[16][68];
  __shared__ float Bs[16][68];
  const int tid = threadIdx.x;
  const int tx = tid & 15, ty = tid >> 4;
  const int row0 = blockIdx.y * 64, col0 = blockIdx.x * 64;
  const int am = tid >> 2, ak = (tid & 3) * 4;
  float acc[4][4] = {};
  for (int k0 = 0; k0 < K; k0 += 16) {
    const float* Ap = A + (long)(row0 + am) * lda + k0 + ak;
#pragma unroll
    for (int j = 0; j < 4; ++j) As[ak + j][am] = Ap[j];
    const float* Bp = B + (long)(col0 + am) * ldb + k0 + ak;
#pragma unroll
    for (int j = 0; j < 4; ++j) Bs[ak + j][am] = Bp[j];
    __syncthreads();
#pragma unroll
    for (int kk = 0; kk < 16; ++kk) {
      float4 av = *(const float4*)&As[kk][ty * 4];
      float4 bv = *(const float4*)&Bs[kk][tx * 4];
      float a[4] = {av.x, av.y, av.z, av.w};
      float b[4] = {bv.x, bv.y, bv.z, bv.w};
#pragma unroll
      for (int i = 0; i < 4; ++i)
#pragma unroll
        for (int j = 0; j < 4; ++j) acc[i][j] += a[i] * b[j];
    }
    __syncthreads();
  }
#pragma unroll
  for (int i = 0; i < 4; ++i) {
    int r = row0 + ty * 4 + i;
#pragma unroll
    for (int j = 0; j < 4; ++j) {
      int c = col0 + tx * 4 + j;
      C[(long)r * ldc + c] = tanhf(acc[i][j]);
    }
  }
}

// ---------------- edge kernels: CSR build + gathers ----------------------------
__global__ __launch_bounds__(256) void count_edges(
    const int* __restrict__ ei, const int* __restrict__ et, float* __restrict__ cnt) {
  int e = blockIdx.x * 256 + threadIdx.x;
  if (e < EE) atomicAdd(&cnt[ei[EE + e] * RR + et[e]], 1.0f);
}

// rowptr from cnt (deg[dst] = sum_r cnt[dst][r]); single block; zero fill[]
__global__ __launch_bounds__(256) void scan_rowptr(
    const float* __restrict__ cntf, int* __restrict__ rowptr, int* __restrict__ fill) {
  __shared__ int part[256];
  int tid = threadIdx.x;
  int base = tid * 32;
  int local[32];
  int s = 0;
  for (int i = 0; i < 32; ++i) {
    local[i] = s;
    const float* c = &cntf[(base + i) * RR];
    int d = 0;
#pragma unroll
    for (int r = 0; r < RR; ++r) d += (int)c[r];
    s += d;
  }
  part[tid] = s;
  __syncthreads();
  for (int off = 1; off < 256; off <<= 1) {
    int v = (tid >= off) ? part[tid - off] : 0;
    __syncthreads();
    part[tid] += v;
    __syncthreads();
  }
  int prev = (tid == 0) ? 0 : part[tid - 1];
  for (int i = 0; i < 32; ++i) rowptr[base + i] = prev + local[i];
  if (tid == 255) rowptr[8192] = part[255];
  for (int i = tid; i < 8192; i += 256) fill[i] = 0;
}

__global__ __launch_bounds__(256) void edge_fill(
    const int* __restrict__ ei, const int* __restrict__ et,
    const int* __restrict__ rowptr, int* __restrict__ fill, int* __restrict__ eidx) {
  int e = blockIdx.x * 256 + threadIdx.x;
  if (e < EE) {
    int dst = ei[EE + e];
    int pos = rowptr[dst] + atomicAdd(&fill[dst], 1);
    eidx[pos] = ei[e] | (et[e] << 16);  // src in low 16, relation in high
  }
}

// out1[dst][h] += sum_edges xw[src][r][h] / max(cnt[dst][r],1); single writer.
__global__ __launch_bounds__(256) void rgcn_gather(
    const int* __restrict__ rowptr, const int* __restrict__ eidx,
    const float* __restrict__ cntf, const float* __restrict__ xw,
    float* __restrict__ out1) {
  const int dst = blockIdx.x;
  const int h = threadIdx.x;
  __shared__ float inv[RR];
  __shared__ int se[256];
  if (h < RR) inv[h] = 1.0f / fmaxf(cntf[dst * RR + h], 1.0f);
  const int beg = rowptr[dst], end = rowptr[dst + 1];
  float acc = 0.f;
  for (int c0 = beg; c0 < end; c0 += 256) {
    int n = min(256, end - c0);
    __syncthreads();
    if (h < n) se[h] = eidx[c0 + h];
    __syncthreads();
    for (int i = 0; i < n; ++i) {
      int pk = se[i];
      int src = pk & 0xFFFF, r = pk >> 16;
      acc += xw[((long)src << 12) + (r << 8) + h] * inv[r];
    }
  }
  out1[((long)dst << 8) + h] += acc;
}

// agg2[dst][h] = sum_edges out1[src][h]; single writer, out1 is L2/LLC-resident.
__global__ __launch_bounds__(256) void graphconv_gather(
    const int* __restrict__ rowptr, const int* __restrict__ eidx,
    const float* __restrict__ out1, float* __restrict__ agg2) {
  const int dst = blockIdx.x;
  const int h = threadIdx.x;
  __shared__ int se[256];
  const int beg = rowptr[dst], end = rowptr[dst + 1];
  float acc = 0.f;
  for (int c0 = beg; c0 < end; c0 += 256) {
    int n = min(256, end - c0);
    __syncthreads();
    if (h < n) se[h] = eidx[c0 + h];
    __syncthreads();
    for (int i = 0; i < n; ++i)
      acc += out1[((long)(se[i] & 0xFFFF) << 8) + h];
  }
  agg2[((long)dst << 8) + h] = acc;
}

// ---------------- copy x (fp32) into emotions[:, 0:512] -----------------------
__global__ __launch_bounds__(256) void copy_x(
    const float* __restrict__ x, float* __restrict__ em) {
  int idx = blockIdx.x * 256 + threadIdx.x;  // 8192*512
  int n = idx >> 9, f = idx & 511;
  em[(long)n * DD + f] = x[idx];
}

// ---------------- softmax over last dim (256) ----------------
__global__ __launch_bounds__(256) void softmax256(float* __restrict__ S) {
  __shared__ float red[256];
  long row = blockIdx.x;
  float* p = S + row * 256;
  int t = threadIdx.x;
  float v = p[t];
  red[t] = v;
  __syncthreads();
  for (int s = 128; s > 0; s >>= 1) {
    if (t < s) red[t] = fmaxf(red[t], red[t + s]);
    __syncthreads();
  }
  float m = red[0];
  __syncthreads();
  float e = __expf(v - m);
  red[t] = e;
  __syncthreads();
  for (int s = 128; s > 0; s >>= 1) {
    if (t < s) red[t] += red[t + s];
    __syncthreads();
  }
  p[t] = e / red[0];
}

// ---------------- logits + log_softmax over batch axis (faithful dim=1) -------
__global__ __launch_bounds__(256) void logits_lsm(
    const float* __restrict__ hidden, const float* __restrict__ w_fc,
    const float* __restrict__ b_fc, void* __restrict__ out_v,
    const int* __restrict__ flag) {
  __shared__ float wf[256 * 7];
  __shared__ float lg[224];
  __shared__ float corr[7];
  int t = blockIdx.x;
  int tid = threadIdx.x;
  for (int i = tid; i < 256 * 7; i += 256) wf[i] = w_fc[i];
  __syncthreads();
  if (tid < 224) {
    int b = tid / 7, c = tid % 7;
    const float* hr = hidden + ((long)((b << 8) + t) << 8);
    float s = b_fc[c];
    for (int k = 0; k < 256; ++k) s += hr[k] * wf[k * 7 + c];
    lg[tid] = s;
  }
  __syncthreads();
  if (tid < 7) {
    float m = -1e30f;
    for (int b = 0; b < BB; ++b) m = fmaxf(m, lg[b * 7 + tid]);
    float sum = 0.f;
    for (int b = 0; b < BB; ++b) sum += __expf(lg[b * 7 + tid] - m);
    corr[tid] = m + logf(sum);
  }
  __syncthreads();
  if (tid < 224) {
    float v = lg[tid] - corr[tid % 7];
    if (flag[0]) ((float*)out_v)[t * 224 + tid] = v;
    else ((__hip_bfloat16*)out_v)[t * 224 + tid] = __float2bfloat16(v);
  }
}

extern "C" void kernel_launch(void* const* d_in, const int* in_sizes, int n_in,
                              void* d_out, int out_size, void* d_ws, size_t ws_size,
                              hipStream_t stream) {
  const int* ei = (const int*)d_in[1];
  const int* et = (const int*)d_in[3];

  float* ws = (float*)d_ws;
  int* flag = (int*)d_ws;
  float* p = ws + 16;
  auto alloc = [&](long nf) { float* r = p; p += nf; return r; };
  float* w_rel_f = alloc(65536);
  float* w_root_f = alloc(65536);
  float* w_fc_f = alloc(1792);
  float* b_rel_f = alloc(256);
  float* bias1_f = alloc(256);
  float* b_att_f = alloc(768);
  float* b_lin_f = alloc(256);
  float* b_fc_f = alloc(16);
  __hip_bfloat16* wlin_hi = (__hip_bfloat16*)alloc(98304);       // [256][768]
  __hip_bfloat16* wlin_lo = (__hip_bfloat16*)alloc(98304);
  float* x_f = alloc(4194304);                                   // [8192][512] fp32
  __hip_bfloat16* x_hi = (__hip_bfloat16*)alloc(2097152);        // [8192][512]
  __hip_bfloat16* x_lo = (__hip_bfloat16*)alloc(2097152);
  __hip_bfloat16* root1_hi = (__hip_bfloat16*)alloc(65536);      // [256][512]
  __hip_bfloat16* root1_lo = (__hip_bfloat16*)alloc(65536);
  __hip_bfloat16* watt_hi = (__hip_bfloat16*)alloc(294912);      // [768][768]
  __hip_bfloat16* watt_lo = (__hip_bfloat16*)alloc(294912);
  __hip_bfloat16* wt_hi = (__hip_bfloat16*)alloc(1048576);       // [4096][512]
  __hip_bfloat16* wt_lo = (__hip_bfloat16*)alloc(1048576);
  float* basis_f = alloc(3932160);
  float* comp_f = alloc(512);
  float* xw = alloc(33554432);   // fp32 [8192][4096]; overlays below
  float* cnt = alloc(131072);
  float* out1 = alloc(2097152);
  float* agg2 = alloc(2097152);
  float* hidden = alloc(2097152);
  int* rowptr = (int*)alloc(8208);
  int* fillc = (int*)alloc(8192);
  int* eidx = (int*)alloc(262144);
  // wt_nat overlays head of xw (consumed by wt_transpose before xw is written)
  float* wt_nat = xw;                                            // [16][512][256]
  // phase B overlays the (consumed) xw region — exactly fills 33,554,432 floats
  float* em = xw;                                                // 6,291,456
  __hip_bfloat16* em_hi = (__hip_bfloat16*)(em + 6291456);       // 3,145,728 f
  __hip_bfloat16* em_lo = (__hip_bfloat16*)(em + 9437184);       // 3,145,728 f
  float* X = em + 12582912;                                      // 6,291,456
  float* scores = em + 18874368;                                 // 2,097,152
  float* att = em + 20971520;                                    // 6,291,456
  __hip_bfloat16* att_hi = (__hip_bfloat16*)(em + 27262976);     // 3,145,728 f
  __hip_bfloat16* att_lo = (__hip_bfloat16*)(em + 30408704);     // 3,145,728 f

  // 0. dtype detect + conversions
  detect_dtype<<<1, 256, 0, stream>>>((const unsigned short*)d_in[0], flag);
  auto cvf = [&](int i, float* dst, int n) {
    int grid = (n + 255) / 256; if (grid > 2048) grid = 2048;
    conv_f32<<<grid, 256, 0, stream>>>(d_in[i], dst, n, flag);
  };
  cvf(0, x_f, NN * FF);
  cvf(8, basis_f, NBASE * FF * HH);
  cvf(9, comp_f, RR * NBASE);
  cvf(11, bias1_f, HH);
  cvf(12, w_rel_f, HH * HH);
  cvf(13, b_rel_f, HH);
  cvf(14, w_root_f, HH * HH);
  cvf(16, b_att_f, DD);
  cvf(18, b_lin_f, HH);
  cvf(19, w_fc_f, HH * CC);
  cvf(20, b_fc_f, CC);
  split_f32<<<2048, 256, 0, stream>>>(x_f, x_hi, x_lo, NN * FF);
  split_t_b16<<<512, 256, 0, stream>>>(d_in[10], root1_hi, root1_lo, FF, HH, flag);
  split_t_b16<<<2048, 256, 0, stream>>>(d_in[15], watt_hi, watt_lo, DD, DD, flag);
  split_t_b16<<<768, 256, 0, stream>>>(d_in[17], wlin_hi, wlin_lo, DD, HH, flag);

  // 1. Wt: coalesced GEMM into natural layout, then LDS-tiled transpose + split
  wt_gemm<<<131072 / 256, 256, 0, stream>>>(basis_f, comp_f, wt_nat);
  wt_transpose<<<dim3(8, 16, 16), 256, 0, stream>>>(wt_nat, wt_hi, wt_lo);
  // 2. xw = x @ W (split A and B, 3 sweeps, fp32 out) [8192][4096]
  mfma_gemm3<<<dim3(4096 / 128, NN / 128), 256, 0, stream>>>(
      x_hi, x_lo, wt_hi, wt_lo, nullptr, xw, FF, 4096, 0);
  // 3. out1 = x @ root1 + bias1 (split A and B)
  mfma_gemm3<<<dim3(HH / 128, NN / 128), 256, 0, stream>>>(
      x_hi, x_lo, root1_hi, root1_lo, bias1_f, out1, FF, HH, FLAG_BIAS);
  // 4. CSR build: per-(dst,rel) counts -> rowptr -> edge fill
  hipMemsetAsync(cnt, 0, 131072 * sizeof(float), stream);
  count_edges<<<EE / 256, 256, 0, stream>>>(ei, et, cnt);
  scan_rowptr<<<1, 256, 0, stream>>>(cnt, rowptr, fillc);
  edge_fill<<<EE / 256, 256, 0, stream>>>(ei, et, rowptr, fillc, eidx);
  // 5. out1 += mean-aggregated messages (gather, no atomics)
  rgcn_gather<<<NN, 256, 0, stream>>>(rowptr, eidx, cnt, xw, out1);
  // 6. agg2 = sum_{src->dst} out1[src] (gather, no atomics)
  graphconv_gather<<<NN, 256, 0, stream>>>(rowptr, eidx, out1, agg2);
  // 7. emotions = [x, out2] (fp32)
  copy_x<<<(NN * FF) / 256, 256, 0, stream>>>(x_f, em);
  gemm_nn<<<dim3(HH / 64, NN / 64, 1), 256, 0, stream>>>(
      agg2, w_rel_f, b_rel_f, em + FF, NN, HH, HH, HH, HH, DD, 0, 0, 0, FLAG_BIAS);
  gemm_nn<<<dim3(HH / 64, NN / 64, 1), 256, 0, stream>>>(
      out1, w_root_f, nullptr, em + FF, NN, HH, HH, HH, HH, DD, 0, 0, 0, FLAG_ACC);
  // 8. X = emotions @ w_att + b_att (split A and B)
  split_f32<<<2048, 256, 0, stream>>>(em, em_hi, em_lo, NN * DD);
  mfma_gemm3<<<dim3(DD / 128, NN / 128), 256, 0, stream>>>(
      em_hi, em_lo, watt_hi, watt_lo, b_att_f, X, DD, DD, FLAG_BIAS);
  // 9. scores = tanh(X_b . Em_b^T) (fp32)
  gemm_nt_tanh<<<dim3(LL / 64, LL / 64, BB), 256, 0, stream>>>(
      X, em, scores, DD, DD, DD, LL, (long)LL * DD, (long)LL * DD, (long)LL * LL);
  // 10. softmax over s
  softmax256<<<BB * LL, 256, 0, stream>>>(scores);
  // 11. att_b = a_b @ Em_b (fp32)
  gemm_nn<<<dim3(DD / 64, LL / 64, BB), 256, 0, stream>>>(
      scores, em, nullptr, att, LL, DD, LL, LL, DD, DD, (long)LL * LL, (long)LL * DD,
      (long)LL * DD, 0);
  // 12. hidden = relu(att @ w_lin + b_lin) (split A and B)
  split_f32<<<2048, 256, 0, stream>>>(att, att_hi, att_lo, NN * DD);
  mfma_gemm3<<<dim3(HH / 128, NN / 128), 256, 0, stream>>>(
      att_hi, att_lo, wlin_hi, wlin_lo, b_lin_f, hidden, DD, HH, FLAG_BIAS | FLAG_RELU);
  // 13. logits + log_softmax over batch axis
  logits_lsm<<<LL, 256, 0, stream>>>(hidden, w_fc_f, b_fc_f, d_out, flag);
}